// Round 13
// baseline (508.836 us; speedup 1.0000x reference)
//
#include <hip/hip_runtime.h>
#include <hip/hip_bf16.h>

// MambaSplit: B=4,C=128,H=W=64, D=64, DI=128, N=16, R=4, K=4, L=4096, E=2*B=8
// Input dtype (bf16 vs f32) detected at runtime; internal compute f32.
// r12 base (atomic direction-merge) + k5/k6a fusion: einsum block == scan chunk,
// phase-2 chunk scan runs entirely from LDS (u/dts/B tiles) -> k6a dispatch gone.

__device__ __forceinline__ float LD(const void* p, size_t i, bool isb) {
  if (isb) {
    unsigned short u = ((const unsigned short*)p)[i];
    return __uint_as_float(((unsigned)u) << 16);
  }
  return ((const float*)p)[i];
}
__device__ __forceinline__ unsigned short f2bf(float f) {
  unsigned u = __float_as_uint(f);
  u = (u + 0x7FFFu + ((u >> 16) & 1u)) >> 16;
  return (unsigned short)u;
}
__device__ __forceinline__ float silu_(float x) { return x / (1.f + __expf(-x)); }
__device__ __forceinline__ float softplus_(float x) {
  return x > 20.f ? x : __logf(1.f + __expf(x));
}
#define EXP2R(x) __builtin_amdgcn_exp2f(x)

// ---------------- detector: bf16 vs f32 input encoding ----------------
__global__ void kdet(const void* x, int* flag) {
  if (threadIdx.x == 0 && blockIdx.x == 0) {
    const unsigned short* xs = (const unsigned short*)x;
    int bad = 0;
    for (int i = 0; i < 64; ++i) {
      int e = (xs[2 * i] >> 7) & 0xFF;
      if (e > 150 || e < 100) bad++;
    }
    *flag = (bad >= 16) ? 0 : 1;
  }
}

// ---------------- K0: dwconv(x) -> T1 (E,L,64) + LN -> T2 ----------------
__global__ __launch_bounds__(256) void k0_conv_ln(
    const void* x, const void* dww, const void* dwb, const void* lg, const void* lb,
    const int* __restrict__ flag,
    float* __restrict__ T1, float* __restrict__ T2)
{
  bool isb = (*flag != 0);
  int e = blockIdx.x >> 6, h = blockIdx.x & 63;
  int b = e & 3, br = e >> 2;
  int t = threadIdx.x;
  __shared__ float sIn[3][64][67];  // [row][d][1+w], w-halo zeroed
  for (int idx = t; idx < 3 * 64; idx += 256) {
    int r = idx >> 6, d = idx & 63;
    sIn[r][d][0] = 0.f; sIn[r][d][65] = 0.f;
  }
  for (int idx = t; idx < 3 * 64 * 64; idx += 256) {
    int r = idx >> 12, rem = idx & 4095, d = rem >> 6, w = rem & 63;
    int hh = h + r - 1;
    float v = 0.f;
    if (hh >= 0 && hh < 64) v = LD(x, ((size_t)(b * 128 + br * 64 + d) * 64 + hh) * 64 + w, isb);
    sIn[r][d][1 + w] = v;
  }
  __syncthreads();
  int w = t >> 2, g = t & 3;
  float vals[16]; float psum = 0.f, psq = 0.f;
#pragma unroll
  for (int j = 0; j < 16; ++j) {
    int d = g * 16 + j, c = br * 64 + d;
    float s = LD(dwb, c, isb);
#pragma unroll
    for (int kh = 0; kh < 3; ++kh)
#pragma unroll
      for (int kw = 0; kw < 3; ++kw)
        s += LD(dww, c * 9 + kh * 3 + kw, isb) * sIn[kh][d][w + kw];
    vals[j] = s; psum += s; psq += s * s;
  }
  size_t base = ((size_t)e * 4096 + h * 64) * 64 + (size_t)t * 16;
#pragma unroll
  for (int j4 = 0; j4 < 4; ++j4) {
    float4 o; o.x = vals[j4*4]; o.y = vals[j4*4+1]; o.z = vals[j4*4+2]; o.w = vals[j4*4+3];
    *(float4*)(T1 + base + j4 * 4) = o;
  }
  __shared__ float sS[64][4], sQ[64][4];
  sS[w][g] = psum; sQ[w][g] = psq;
  __syncthreads();
  float m = (sS[w][0] + sS[w][1] + sS[w][2] + sS[w][3]) * (1.f / 64.f);
  float q = (sQ[w][0] + sQ[w][1] + sQ[w][2] + sQ[w][3]) * (1.f / 64.f);
  float rs = rsqrtf(q - m * m + 1e-5f);
#pragma unroll
  for (int j4 = 0; j4 < 4; ++j4) {
    float tmp[4];
#pragma unroll
    for (int jj = 0; jj < 4; ++jj) {
      int j = j4 * 4 + jj; int d = g * 16 + j;
      tmp[jj] = (vals[j] - m) * rs * LD(lg, d, isb) + LD(lb, d, isb);
    }
    float4 o; o.x = tmp[0]; o.y = tmp[1]; o.z = tmp[2]; o.w = tmp[3];
    *(float4*)(T2 + base + j4 * 4) = o;
  }
}

// ---------------- K2: in_proj GEMM  T2(32768,64) @ W^T(64,256) -> T3 / T4 ----------------
__global__ __launch_bounds__(256) void k2_inproj(
    const float* __restrict__ T2, const void* Wip, const int* __restrict__ flag,
    float* __restrict__ T3, float* __restrict__ T4)
{
  bool isb = (*flag != 0);
  int mt = blockIdx.x, ct = blockIdx.y;
  int t = threadIdx.x;
  __shared__ float sA[64][68];  // [d][l]
  __shared__ float sB[64][68];  // [d][c]
  int row0 = mt * 64;
  for (int q = t; q < 1024; q += 256) {
    int l = q >> 4, d4 = (q & 15) * 4;
    float4 v = *(const float4*)(T2 + (size_t)(row0 + l) * 64 + d4);
    sA[d4][l] = v.x; sA[d4+1][l] = v.y; sA[d4+2][l] = v.z; sA[d4+3][l] = v.w;
  }
  for (int q = t; q < 1024; q += 256) {
    int cl = q >> 4, d4 = (q & 15) * 4;
    size_t base = (size_t)(ct * 64 + cl) * 64 + d4;
    sB[d4][cl]   = LD(Wip, base, isb);
    sB[d4+1][cl] = LD(Wip, base + 1, isb);
    sB[d4+2][cl] = LD(Wip, base + 2, isb);
    sB[d4+3][cl] = LD(Wip, base + 3, isb);
  }
  __syncthreads();
  int ty = t >> 4, tx = t & 15;
  float acc[4][4];
#pragma unroll
  for (int i = 0; i < 4; ++i)
#pragma unroll
    for (int j = 0; j < 4; ++j) acc[i][j] = 0.f;
  for (int kk = 0; kk < 64; ++kk) {
    float4 a = *(const float4*)&sA[kk][ty * 4];
    float4 bq = *(const float4*)&sB[kk][tx * 4];
    float aa[4] = {a.x, a.y, a.z, a.w}, bb[4] = {bq.x, bq.y, bq.z, bq.w};
#pragma unroll
    for (int i = 0; i < 4; ++i)
#pragma unroll
      for (int j = 0; j < 4; ++j) acc[i][j] += aa[i] * bb[j];
  }
  int c0 = ct * 64 + tx * 4;
#pragma unroll
  for (int i = 0; i < 4; ++i) {
    size_t row = (size_t)row0 + ty * 4 + i;
    float4 o;
    if (c0 < 128) {
      o.x = acc[i][0]; o.y = acc[i][1]; o.z = acc[i][2]; o.w = acc[i][3];
      *(float4*)(T3 + row * 128 + c0) = o;
    } else {
      o.x = silu_(acc[i][0]); o.y = silu_(acc[i][1]); o.z = silu_(acc[i][2]); o.w = silu_(acc[i][3]);
      *(float4*)(T4 + row * 128 + (c0 - 128)) = o;
    }
  }
}

// ---------------- K3: depthwise conv 3x3 + SiLU -> U0[h*64+w][c], U1[w*64+h][c] ----------------
__global__ __launch_bounds__(256) void k3_conv2(
    const float* __restrict__ T3, const void* cw, const void* cb, const int* __restrict__ flag,
    float* __restrict__ U0, float* __restrict__ U1)
{
  bool isb = (*flag != 0);
  int e = blockIdx.x >> 6, h = blockIdx.x & 63, dc = blockIdx.y;
  int t = threadIdx.x;
  __shared__ float sI[3][66][65];  // [row][1+w][d]
  for (int idx = t; idx < 3 * 2 * 64; idx += 256) {
    int r = idx / 128, rem = idx % 128, side = rem >> 6, d = rem & 63;
    sI[r][side * 65][d] = 0.f;
  }
  for (int idx = t; idx < 3 * 64 * 64; idx += 256) {
    int r = idx >> 12, rem = idx & 4095, w = rem >> 6, d = rem & 63;
    int hh = h + r - 1;
    float v = 0.f;
    if (hh >= 0 && hh < 64) v = T3[((size_t)e * 4096 + hh * 64 + w) * 128 + dc * 64 + d];
    sI[r][1 + w][d] = v;
  }
  __syncthreads();
  int d = t & 63, wq = t >> 6;
  int c2 = dc * 64 + d;
  float wt[9];
#pragma unroll
  for (int m = 0; m < 9; ++m) wt[m] = LD(cw, c2 * 9 + m, isb);
  float bias = LD(cb, c2, isb);
  size_t eb = (size_t)e * 4096;
#pragma unroll
  for (int i = 0; i < 16; ++i) {
    int w = wq * 16 + i;
    float s = bias;
#pragma unroll
    for (int kh = 0; kh < 3; ++kh)
#pragma unroll
      for (int kw = 0; kw < 3; ++kw)
        s += wt[kh * 3 + kw] * sI[kh][w + kw][d];
    s = silu_(s);
    U0[(eb + h * 64 + w) * 128 + c2] = s;
    U1[(eb + w * 64 + h) * 128 + c2] = s;
  }
}

// ---------------- K56: x_dbl einsum + chunk-local scan fused (chunk = 64 rows) ----------------
__global__ __launch_bounds__(256) void k56_xdbl_scan(
    const float* __restrict__ U0, const float* __restrict__ U1,
    const void* xpw, const void* alog, const void* dtw, const void* dtb,
    const int* __restrict__ flag,
    float* __restrict__ dts4, float* __restrict__ Bb2, float* __restrict__ Cb2,
    float* __restrict__ Hs)
{
  bool isb = (*flag != 0);
  int lt = blockIdx.x;   // chunk index, 64 chunks of 64 rows
  int ek = blockIdx.y;   // e*4+k
  int e = ek >> 2, k = ek & 3;
  int ls0 = lt * 64;
  int t = threadIdx.x;
  __shared__ float sU[64][132];   // [l][d] scan-order rows
  __shared__ float sW[36][128];   // [c][d] (broadcast reads, no pad needed)
  __shared__ float sDts[64][4];
  __shared__ float sBl[64][16];
  for (int idx = t; idx < 36 * 128; idx += 256) {
    int c = idx >> 7, d = idx & 127;
    sW[c][d] = LD(xpw, ((size_t)k * 36 + c) * 128 + d, isb);
  }
  const float* usrc = (k & 1) ? U1 : U0;
  bool rev = (k >= 2);
  for (int idx = t; idx < 2048; idx += 256) {
    int l = idx >> 5, d4 = (idx & 31) * 4;
    int row = rev ? (4095 - ls0 - l) : (ls0 + l);
    float4 v = *(const float4*)(usrc + ((size_t)e * 4096 + row) * 128 + d4);
    *(float4*)&sU[l][d4] = v;
  }
  __syncthreads();
  {
    int l = t & 63, cg = t >> 6;
    float acc[9];
#pragma unroll
    for (int j = 0; j < 9; ++j) acc[j] = 0.f;
    for (int dd = 0; dd < 32; ++dd) {
      float4 u4 = *(const float4*)&sU[l][dd * 4];
      float ua[4] = {u4.x, u4.y, u4.z, u4.w};
#pragma unroll
      for (int j = 0; j < 9; ++j) {
        float4 w4 = *(const float4*)&sW[cg * 9 + j][dd * 4];
        acc[j] += ua[0] * w4.x + ua[1] * w4.y + ua[2] * w4.z + ua[3] * w4.w;
      }
    }
    size_t row = (size_t)ek * 4096 + ls0 + l;
#pragma unroll
    for (int j = 0; j < 9; ++j) {
      int c = cg * 9 + j;
      if (c < 4) { dts4[row * 4 + c] = acc[j]; sDts[l][c] = acc[j]; }
      else if (c < 20) { Bb2[row * 16 + (c - 4)] = acc[j]; sBl[l][c - 4] = acc[j]; }
      else Cb2[row * 16 + (c - 20)] = acc[j];
    }
  }
  __syncthreads();
  if (t >= 128) return;
  // ---- phase 2: 64-step chunk scan from LDS; d = t ----
  int d = t;
  float a2[16];
#pragma unroll
  for (int n = 0; n < 16; ++n)
    a2[n] = -__expf(LD(alog, ((size_t)k * 128 + d) * 16 + n, isb)) * 1.44269504f;
  float w0 = LD(dtw, ((size_t)k * 128 + d) * 4 + 0, isb);
  float w1 = LD(dtw, ((size_t)k * 128 + d) * 4 + 1, isb);
  float w2 = LD(dtw, ((size_t)k * 128 + d) * 4 + 2, isb);
  float w3 = LD(dtw, ((size_t)k * 128 + d) * 4 + 3, isb);
  float bd = LD(dtb, k * 128 + d, isb);
  float h[16];
#pragma unroll
  for (int n = 0; n < 16; ++n) h[n] = 0.f;
  float sdelta = 0.f;
#pragma unroll 2
  for (int t2 = 0; t2 < 64; ++t2) {
    float4 s4 = *(const float4*)&sDts[t2][0];
    float xv = bd + w0 * s4.x + w1 * s4.y + w2 * s4.z + w3 * s4.w;
    float dlt = softplus_(xv);
    float uu = sU[t2][d];
    float du = dlt * uu;
    float4 b0 = *(const float4*)&sBl[t2][0];
    float4 b1 = *(const float4*)&sBl[t2][4];
    float4 b2 = *(const float4*)&sBl[t2][8];
    float4 b3 = *(const float4*)&sBl[t2][12];
    float bb[16] = {b0.x,b0.y,b0.z,b0.w, b1.x,b1.y,b1.z,b1.w,
                    b2.x,b2.y,b2.z,b2.w, b3.x,b3.y,b3.z,b3.w};
    sdelta += dlt;
#pragma unroll
    for (int n = 0; n < 16; ++n) {
      float dA = EXP2R(dlt * a2[n]);
      h[n] = fmaf(dA, h[n], du * bb[n]);
    }
  }
  float2* hp = (float2*)Hs + ((size_t)lt * 65536 + ek * 2048 + d * 16);
#pragma unroll
  for (int n = 0; n < 16; ++n) {
    float2 o; o.x = h[n]; o.y = EXP2R(a2[n] * sdelta);  // telescoped prod(dA)
    hp[n] = o;
  }
}

// ---------------- K6b: carry scan over chunk summaries; carry written IN-PLACE into Hs.x ----------------
__global__ __launch_bounds__(256) void k6b_carry(
    float* __restrict__ Hs, int nchunks)
{
  int idx = blockIdx.x * 256 + threadIdx.x;   // 65536 rows
  float2* hs = (float2*)Hs;
  float carry = 0.f;
  for (int c = 0; c < nchunks; ++c) {
    float2 v = hs[(size_t)c * 65536 + idx];
    Hs[((size_t)c * 65536 + idx) * 2] = carry;   // overwrite .x with incoming state
    carry = v.x + v.y * carry;
  }
}

// ---------------- K6c: seeded chunk scan, delta fused; y atomically merged into Ysum ----------------
template<int NSTEPS>
__global__ __launch_bounds__(128) void k6c_apply(
    const float* __restrict__ U0, const float* __restrict__ U1,
    float* __restrict__ Ysum, const float* __restrict__ dts4,
    const float* __restrict__ Bb2, const float* __restrict__ Cb2,
    const void* alog, const void* dtw, const void* dtb,
    const float* __restrict__ Hs, const int* __restrict__ flag)
{
  bool isb = (*flag != 0);
  int chunk = blockIdx.x, ek = blockIdx.y;
  int e = ek >> 2, k = ek & 3;
  int d = threadIdx.x;
  int ls0 = chunk * NSTEPS;
  float a2[16];
#pragma unroll
  for (int n = 0; n < 16; ++n)
    a2[n] = -__expf(LD(alog, ((size_t)k * 128 + d) * 16 + n, isb)) * 1.44269504f;
  float w0 = LD(dtw, ((size_t)k * 128 + d) * 4 + 0, isb);
  float w1 = LD(dtw, ((size_t)k * 128 + d) * 4 + 1, isb);
  float w2 = LD(dtw, ((size_t)k * 128 + d) * 4 + 2, isb);
  float w3 = LD(dtw, ((size_t)k * 128 + d) * 4 + 3, isb);
  float bd = LD(dtb, k * 128 + d, isb);
  float h[16];
  const float* hp = Hs + ((size_t)chunk * 65536 + ek * 2048 + d * 16) * 2;
#pragma unroll
  for (int n = 0; n < 16; ++n) h[n] = hp[2 * n];
  const float* usrc = (k & 1) ? U1 : U0;
  const bool rev = (k >= 2);
  float* ybase = Ysum + (size_t)e * 4096 * 128 + d;
  const float* ubase = usrc + (size_t)e * 4096 * 128 + d;
  const float4* sbase = (const float4*)(dts4 + ((size_t)ek * 4096 + ls0) * 4);
  const float4* bbase = (const float4*)(Bb2 + ((size_t)ek * 4096 + ls0) * 16);
  const float4* cbase = (const float4*)(Cb2 + ((size_t)ek * 4096 + ls0) * 16);
#pragma unroll 2
  for (int t = 0; t < NSTEPS; ++t) {
    float4 s4 = sbase[t];
    float xv = bd + w0 * s4.x + w1 * s4.y + w2 * s4.z + w3 * s4.w;
    float dlt = softplus_(xv);
    int urow = rev ? (4095 - ls0 - t) : (ls0 + t);
    float uu = ubase[(size_t)urow * 128];
    float du = dlt * uu;
    float4 b0 = bbase[t * 4 + 0], b1 = bbase[t * 4 + 1], b2 = bbase[t * 4 + 2], b3 = bbase[t * 4 + 3];
    float4 c0 = cbase[t * 4 + 0], c1 = cbase[t * 4 + 1], c2 = cbase[t * 4 + 2], c3 = cbase[t * 4 + 3];
    float bb[16] = {b0.x,b0.y,b0.z,b0.w, b1.x,b1.y,b1.z,b1.w,
                    b2.x,b2.y,b2.z,b2.w, b3.x,b3.y,b3.z,b3.w};
    float cc[16] = {c0.x,c0.y,c0.z,c0.w, c1.x,c1.y,c1.z,c1.w,
                    c2.x,c2.y,c2.z,c2.w, c3.x,c3.y,c3.z,c3.w};
    float ya = 0.f, yb = 0.f, yc = 0.f, yd = 0.f;
#pragma unroll
    for (int n = 0; n < 16; n += 4) {
      float dA0 = EXP2R(dlt * a2[n]);
      float dA1 = EXP2R(dlt * a2[n+1]);
      float dA2 = EXP2R(dlt * a2[n+2]);
      float dA3 = EXP2R(dlt * a2[n+3]);
      h[n]   = fmaf(dA0, h[n],   du * bb[n]);
      h[n+1] = fmaf(dA1, h[n+1], du * bb[n+1]);
      h[n+2] = fmaf(dA2, h[n+2], du * bb[n+2]);
      h[n+3] = fmaf(dA3, h[n+3], du * bb[n+3]);
      ya = fmaf(h[n],   cc[n],   ya);
      yb = fmaf(h[n+1], cc[n+1], yb);
      yc = fmaf(h[n+2], cc[n+2], yc);
      yd = fmaf(h[n+3], cc[n+3], yd);
    }
    // map scan position -> output spatial row, then atomic merge
    int p = ls0 + t;
    int orow;
    if (k == 0)      orow = p;
    else if (k == 1) orow = ((p & 63) << 6) | (p >> 6);
    else if (k == 2) orow = 4095 - p;
    else { int q = 4095 - p; orow = ((q & 63) << 6) | (q >> 6); }
    atomicAdd(ybase + (size_t)orow * 128, (ya + yb) + (yc + yd));
  }
}

// ---------------- K init: Ysum[e,l,d] = sum_k(Ds)*u ----------------
__global__ __launch_bounds__(256) void k_init_ysum(
    const float* __restrict__ U0, const void* Ds, const int* __restrict__ flag,
    float* __restrict__ Ysum)
{
  bool isb = (*flag != 0);
  size_t idx = ((size_t)blockIdx.x * 256 + threadIdx.x) * 4;  // over 4,194,304 floats
  int d = (int)(idx & 127);
  float4 u = *(const float4*)(U0 + idx);
  float s0 = LD(Ds, d + 0, isb) + LD(Ds, 128 + d + 0, isb) + LD(Ds, 256 + d + 0, isb) + LD(Ds, 384 + d + 0, isb);
  float s1 = LD(Ds, d + 1, isb) + LD(Ds, 128 + d + 1, isb) + LD(Ds, 256 + d + 1, isb) + LD(Ds, 384 + d + 1, isb);
  float s2 = LD(Ds, d + 2, isb) + LD(Ds, 128 + d + 2, isb) + LD(Ds, 256 + d + 2, isb) + LD(Ds, 384 + d + 2, isb);
  float s3 = LD(Ds, d + 3, isb) + LD(Ds, 128 + d + 3, isb) + LD(Ds, 256 + d + 3, isb) + LD(Ds, 384 + d + 3, isb);
  float4 o; o.x = s0 * u.x; o.y = s1 * u.y; o.z = s2 * u.z; o.w = s3 * u.w;
  *(float4*)(Ysum + idx) = o;
}

// ---------------- K7b: out_norm LN * silu(z) -> out_proj -> +residual -> P (E,64,L) ----------------
__global__ __launch_bounds__(256) void k7b_out(
    const float* __restrict__ Ysum, const float* __restrict__ T4,
    const float* __restrict__ T1,
    const void* ong, const void* onb, const void* opw, const void* scale_p,
    const int* __restrict__ flag,
    float* __restrict__ P)
{
  bool isb = (*flag != 0);
  int bid = blockIdx.x; int e = bid >> 7, lt = bid & 127;
  int l0 = lt * 32;
  int t = threadIdx.x;
  __shared__ float sY[32][132];
  __shared__ float sWo[64][132];
  __shared__ float sMu[32], sRs[32];
  __shared__ float sPs[32][8], sPq[32][8];
  __shared__ float sP[64][33];
  for (int idx = t; idx < 8192; idx += 256) sWo[idx >> 7][idx & 127] = LD(opw, idx, isb);
  for (int q = t; q < 1024; q += 256) {
    int l = q >> 5, d4 = (q & 31) * 4;
    float4 v = *(const float4*)(Ysum + ((size_t)e * 4096 + l0 + l) * 128 + d4);
    *(float4*)&sY[l][d4] = v;
  }
  __syncthreads();
  {
    int l = t & 31, g = t >> 5;
    float s = 0.f, q2 = 0.f;
#pragma unroll
    for (int j = 0; j < 16; ++j) { float v = sY[l][g * 16 + j]; s += v; q2 += v * v; }
    sPs[l][g] = s; sPq[l][g] = q2;
  }
  __syncthreads();
  if (t < 32) {
    float s = 0.f, q2 = 0.f;
#pragma unroll
    for (int g = 0; g < 8; ++g) { s += sPs[t][g]; q2 += sPq[t][g]; }
    float mu = s * (1.f / 128.f);
    float var = q2 * (1.f / 128.f) - mu * mu;
    sMu[t] = mu; sRs[t] = rsqrtf(var + 1e-5f);
  }
  __syncthreads();
  for (int idx = t; idx < 4096; idx += 256) {
    int l = idx >> 7, dd2 = idx & 127;
    float v = (sY[l][dd2] - sMu[l]) * sRs[l] * LD(ong, dd2, isb) + LD(onb, dd2, isb);
    v *= T4[((size_t)e * 4096 + l0 + l) * 128 + dd2];
    sY[l][dd2] = v;
  }
  __syncthreads();
  float ops = 1.f + LD(scale_p, 0, isb);
  {
    int l = t & 31, cg = t >> 5;
    float acc[8];
#pragma unroll
    for (int j = 0; j < 8; ++j) acc[j] = 0.f;
    for (int dd = 0; dd < 32; ++dd) {
      float4 v4 = *(const float4*)&sY[l][dd * 4];
      float va[4] = {v4.x, v4.y, v4.z, v4.w};
#pragma unroll
      for (int j = 0; j < 8; ++j) {
        float4 w4 = *(const float4*)&sWo[cg * 8 + j][dd * 4];
        acc[j] += va[0] * w4.x + va[1] * w4.y + va[2] * w4.z + va[3] * w4.w;
      }
    }
#pragma unroll
    for (int j = 0; j < 8; ++j) {
      int c = cg * 8 + j;
      sP[c][l] = acc[j] + ops * T1[((size_t)e * 4096 + l0 + l) * 64 + c];
    }
  }
  __syncthreads();
  for (int q = t; q < 512; q += 256) {
    int c = q >> 3, lq = (q & 7) * 4;
    float4 o; o.x = sP[c][lq]; o.y = sP[c][lq+1]; o.z = sP[c][lq+2]; o.w = sP[c][lq+3];
    *(float4*)(P + ((size_t)e * 64 + c) * 4096 + l0 + lq) = o;
  }
}

// ---------------- K7c: instance-norm over L per (e,c) + leaky relu + out ----------------
__global__ __launch_bounds__(256) void k7c_final(
    const float* __restrict__ P, const void* gamma, const void* beta,
    const int* __restrict__ flag, void* __restrict__ out)
{
  bool isb = (*flag != 0);
  int bid = blockIdx.x; int e = bid >> 6, c = bid & 63;
  int b = e & 3, br = e >> 2;
  int cg = br * 64 + c;
  int t = threadIdx.x;
  const float* p = P + ((size_t)e * 64 + c) * 4096;
  float s = 0.f, q2 = 0.f;
  for (int q = t; q < 1024; q += 256) {
    float4 v = *(const float4*)(p + q * 4);
    s += v.x + v.y + v.z + v.w;
    q2 += v.x * v.x + v.y * v.y + v.z * v.z + v.w * v.w;
  }
#pragma unroll
  for (int off = 1; off < 64; off <<= 1) { s += __shfl_xor(s, off); q2 += __shfl_xor(q2, off); }
  __shared__ float rS[4], rQ[4];
  if ((t & 63) == 0) { rS[t >> 6] = s; rQ[t >> 6] = q2; }
  __syncthreads();
  float ts = rS[0] + rS[1] + rS[2] + rS[3];
  float tq = rQ[0] + rQ[1] + rQ[2] + rQ[3];
  float mu = ts * (1.f / 4096.f);
  float var = tq * (1.f / 4096.f) - mu * mu;
  float rsg = rsqrtf(var + 1e-5f);
  float gm = LD(gamma, cg, isb), bt = LD(beta, cg, isb);
  size_t obase = ((size_t)(b * 128 + cg)) * 4096;
  for (int q = t; q < 1024; q += 256) {
    float4 v = *(const float4*)(p + q * 4);
    float o0 = (v.x - mu) * rsg * gm + bt; o0 = o0 > 0.f ? o0 : 0.01f * o0;
    float o1 = (v.y - mu) * rsg * gm + bt; o1 = o1 > 0.f ? o1 : 0.01f * o1;
    float o2 = (v.z - mu) * rsg * gm + bt; o2 = o2 > 0.f ? o2 : 0.01f * o2;
    float o3 = (v.w - mu) * rsg * gm + bt; o3 = o3 > 0.f ? o3 : 0.01f * o3;
    if (isb) {
      unsigned short* op = (unsigned short*)out + obase;
      unsigned lo = (unsigned)f2bf(o0) | ((unsigned)f2bf(o1) << 16);
      unsigned hi = (unsigned)f2bf(o2) | ((unsigned)f2bf(o3) << 16);
      uint2 u; u.x = lo; u.y = hi;
      *(uint2*)(op + q * 4) = u;
    } else {
      float* op = (float*)out + obase;
      float4 o; o.x = o0; o.y = o1; o.z = o2; o.w = o3;
      *(float4*)(op + q * 4) = o;
    }
  }
}

extern "C" void kernel_launch(void* const* d_in, const int* in_sizes, int n_in,
                              void* d_out, int out_size, void* d_ws, size_t ws_size,
                              hipStream_t stream) {
  (void)in_sizes; (void)n_in; (void)out_size;
  const void* x      = d_in[0];
  const void* dw_w   = d_in[1];
  const void* dw_b   = d_in[2];
  const void* scale  = d_in[3];
  const void* ln1_g  = d_in[4];
  const void* ln1_b  = d_in[5];
  const void* ipw    = d_in[6];
  const void* conv_w = d_in[7];
  const void* conv_b = d_in[8];
  const void* xpw    = d_in[9];
  const void* dtw    = d_in[10];
  const void* dtb    = d_in[11];
  const void* alog   = d_in[12];
  const void* Ds     = d_in[13];
  const void* ong    = d_in[14];
  const void* onb    = d_in[15];
  const void* opw    = d_in[16];
  const void* ing    = d_in[17];
  const void* inb    = d_in[18];

  float* ws = (float*)d_ws;
  float* T1  = ws;                   // (E,L,64)  xd rows                 8.4MB
  float* T2  = ws + 2097152;         // (E,L,64)  xln -> dts4 -> P        8.4MB
  float* T3  = ws + 4194304;         // (E,L,128) conv-in -> Bb2+Cb2      16.8MB
  float* T4  = ws + 8388608;         // (E,L,128) silu(z)                 16.8MB
  float* U0  = ws + 12582912;        // (E,L,128) xc rows [h*64+w][d]     16.8MB
  float* U1  = ws + 16777216;        // (E,L,128) xc rows [w*64+h][d]     16.8MB
  float* Ysum = ws + 20971520;       // (E,L,128) direction-merged y      16.8MB
  float* Bb2 = T3;                   // (EK,L,16)
  float* Cb2 = T3 + 2097152;         // (EK,L,16)
  float* Hs  = ws + 37748736;        // 64 x 65536 float2 (carry in-place)
  float* dts4 = T2;                  // (EK,L,4) — overlays dead xln

  size_t base_f = 37748736;
  size_t need64 = (base_f + (size_t)64 * 65536 * 2 + 16) * 4;
  bool big = (ws_size >= need64);
  int nch = big ? 64 : 32;
  int* flag = (int*)(ws + base_f + (size_t)nch * 65536 * 2);

  hipLaunchKernelGGL(kdet, dim3(1), dim3(64), 0, stream, x, flag);
  hipLaunchKernelGGL(k0_conv_ln, dim3(512), dim3(256), 0, stream, x, dw_w, dw_b, ln1_g, ln1_b, flag, T1, T2);
  hipLaunchKernelGGL(k2_inproj, dim3(512, 4), dim3(256), 0, stream, T2, ipw, flag, T3, T4);
  hipLaunchKernelGGL(k3_conv2, dim3(512, 2), dim3(256), 0, stream, T3, conv_w, conv_b, flag, U0, U1);
  hipLaunchKernelGGL(k_init_ysum, dim3(4096), dim3(256), 0, stream, U0, Ds, flag, Ysum);
  if (big) {
    // fused einsum + chunk scan (64 chunks of 64)
    hipLaunchKernelGGL(k56_xdbl_scan, dim3(64, 32), dim3(256), 0, stream,
                       U0, U1, xpw, alog, dtw, dtb, flag, dts4, Bb2, Cb2, Hs);
    hipLaunchKernelGGL(k6b_carry, dim3(256), dim3(256), 0, stream, Hs, 64);
    hipLaunchKernelGGL(k6c_apply<64>, dim3(64, 32), dim3(128), 0, stream, U0, U1, Ysum, dts4, Bb2, Cb2, alog, dtw, dtb, Hs, flag);
  } else {
    // fallback: fused kernel at 64 chunks needs 33.6MB Hs; with smaller ws use
    // the same fused kernel writing a 32-chunk Hs is not layout-compatible, so
    // run fused with 64 chunks only when ws allows; otherwise emulate via two
    // fused halves is overkill — use fused kernel anyway requires Hs64; so for
    // small ws run fused with Hs32 by treating pairs: NOT supported — fall back
    // to 32-chunk scan using k6c-style recompute for summaries.
    hipLaunchKernelGGL(k56_xdbl_scan, dim3(64, 32), dim3(256), 0, stream,
                       U0, U1, xpw, alog, dtw, dtb, flag, dts4, Bb2, Cb2, Hs);
    hipLaunchKernelGGL(k6b_carry, dim3(256), dim3(256), 0, stream, Hs, 64);
    hipLaunchKernelGGL(k6c_apply<64>, dim3(64, 32), dim3(128), 0, stream, U0, U1, Ysum, dts4, Bb2, Cb2, alog, dtw, dtb, Hs, flag);
  }
  hipLaunchKernelGGL(k7b_out, dim3(1024), dim3(256), 0, stream, Ysum, T4, T1, ong, onb, opw, scale, flag, T2);
  hipLaunchKernelGGL(k7c_final, dim3(512), dim3(256), 0, stream, T2, ing, inb, flag, d_out);
}

// Round 14
// 458.019 us; speedup vs baseline: 1.1109x; 1.1109x over previous
//
#include <hip/hip_runtime.h>
#include <hip/hip_bf16.h>

// MambaSplit: B=4,C=128,H=W=64, D=64, DI=128, N=16, R=4, K=4, L=4096, E=2*B=8
// Input dtype (bf16 vs f32) detected at runtime; internal compute f32.
// Round-12 structure (best: 467us): separate k5/k6a/k6b/k6c, atomic direction-
// merge into Ysum. This round: Ysum init (sumDs*u) folded into k3.

__device__ __forceinline__ float LD(const void* p, size_t i, bool isb) {
  if (isb) {
    unsigned short u = ((const unsigned short*)p)[i];
    return __uint_as_float(((unsigned)u) << 16);
  }
  return ((const float*)p)[i];
}
__device__ __forceinline__ unsigned short f2bf(float f) {
  unsigned u = __float_as_uint(f);
  u = (u + 0x7FFFu + ((u >> 16) & 1u)) >> 16;
  return (unsigned short)u;
}
__device__ __forceinline__ float silu_(float x) { return x / (1.f + __expf(-x)); }
__device__ __forceinline__ float softplus_(float x) {
  return x > 20.f ? x : __logf(1.f + __expf(x));
}
#define EXP2R(x) __builtin_amdgcn_exp2f(x)

// ---------------- detector: bf16 vs f32 input encoding ----------------
__global__ void kdet(const void* x, int* flag) {
  if (threadIdx.x == 0 && blockIdx.x == 0) {
    const unsigned short* xs = (const unsigned short*)x;
    int bad = 0;
    for (int i = 0; i < 64; ++i) {
      int e = (xs[2 * i] >> 7) & 0xFF;
      if (e > 150 || e < 100) bad++;
    }
    *flag = (bad >= 16) ? 0 : 1;
  }
}

// ---------------- K0: dwconv(x) -> T1 (E,L,64) + LN -> T2 ----------------
__global__ __launch_bounds__(256) void k0_conv_ln(
    const void* x, const void* dww, const void* dwb, const void* lg, const void* lb,
    const int* __restrict__ flag,
    float* __restrict__ T1, float* __restrict__ T2)
{
  bool isb = (*flag != 0);
  int e = blockIdx.x >> 6, h = blockIdx.x & 63;
  int b = e & 3, br = e >> 2;
  int t = threadIdx.x;
  __shared__ float sIn[3][64][67];  // [row][d][1+w], w-halo zeroed
  for (int idx = t; idx < 3 * 64; idx += 256) {
    int r = idx >> 6, d = idx & 63;
    sIn[r][d][0] = 0.f; sIn[r][d][65] = 0.f;
  }
  for (int idx = t; idx < 3 * 64 * 64; idx += 256) {
    int r = idx >> 12, rem = idx & 4095, d = rem >> 6, w = rem & 63;
    int hh = h + r - 1;
    float v = 0.f;
    if (hh >= 0 && hh < 64) v = LD(x, ((size_t)(b * 128 + br * 64 + d) * 64 + hh) * 64 + w, isb);
    sIn[r][d][1 + w] = v;
  }
  __syncthreads();
  int w = t >> 2, g = t & 3;
  float vals[16]; float psum = 0.f, psq = 0.f;
#pragma unroll
  for (int j = 0; j < 16; ++j) {
    int d = g * 16 + j, c = br * 64 + d;
    float s = LD(dwb, c, isb);
#pragma unroll
    for (int kh = 0; kh < 3; ++kh)
#pragma unroll
      for (int kw = 0; kw < 3; ++kw)
        s += LD(dww, c * 9 + kh * 3 + kw, isb) * sIn[kh][d][w + kw];
    vals[j] = s; psum += s; psq += s * s;
  }
  size_t base = ((size_t)e * 4096 + h * 64) * 64 + (size_t)t * 16;
#pragma unroll
  for (int j4 = 0; j4 < 4; ++j4) {
    float4 o; o.x = vals[j4*4]; o.y = vals[j4*4+1]; o.z = vals[j4*4+2]; o.w = vals[j4*4+3];
    *(float4*)(T1 + base + j4 * 4) = o;
  }
  __shared__ float sS[64][4], sQ[64][4];
  sS[w][g] = psum; sQ[w][g] = psq;
  __syncthreads();
  float m = (sS[w][0] + sS[w][1] + sS[w][2] + sS[w][3]) * (1.f / 64.f);
  float q = (sQ[w][0] + sQ[w][1] + sQ[w][2] + sQ[w][3]) * (1.f / 64.f);
  float rs = rsqrtf(q - m * m + 1e-5f);
#pragma unroll
  for (int j4 = 0; j4 < 4; ++j4) {
    float tmp[4];
#pragma unroll
    for (int jj = 0; jj < 4; ++jj) {
      int j = j4 * 4 + jj; int d = g * 16 + j;
      tmp[jj] = (vals[j] - m) * rs * LD(lg, d, isb) + LD(lb, d, isb);
    }
    float4 o; o.x = tmp[0]; o.y = tmp[1]; o.z = tmp[2]; o.w = tmp[3];
    *(float4*)(T2 + base + j4 * 4) = o;
  }
}

// ---------------- K2: in_proj GEMM  T2(32768,64) @ W^T(64,256) -> T3 / T4 ----------------
__global__ __launch_bounds__(256) void k2_inproj(
    const float* __restrict__ T2, const void* Wip, const int* __restrict__ flag,
    float* __restrict__ T3, float* __restrict__ T4)
{
  bool isb = (*flag != 0);
  int mt = blockIdx.x, ct = blockIdx.y;
  int t = threadIdx.x;
  __shared__ float sA[64][68];  // [d][l]
  __shared__ float sB[64][68];  // [d][c]
  int row0 = mt * 64;
  for (int q = t; q < 1024; q += 256) {
    int l = q >> 4, d4 = (q & 15) * 4;
    float4 v = *(const float4*)(T2 + (size_t)(row0 + l) * 64 + d4);
    sA[d4][l] = v.x; sA[d4+1][l] = v.y; sA[d4+2][l] = v.z; sA[d4+3][l] = v.w;
  }
  for (int q = t; q < 1024; q += 256) {
    int cl = q >> 4, d4 = (q & 15) * 4;
    size_t base = (size_t)(ct * 64 + cl) * 64 + d4;
    sB[d4][cl]   = LD(Wip, base, isb);
    sB[d4+1][cl] = LD(Wip, base + 1, isb);
    sB[d4+2][cl] = LD(Wip, base + 2, isb);
    sB[d4+3][cl] = LD(Wip, base + 3, isb);
  }
  __syncthreads();
  int ty = t >> 4, tx = t & 15;
  float acc[4][4];
#pragma unroll
  for (int i = 0; i < 4; ++i)
#pragma unroll
    for (int j = 0; j < 4; ++j) acc[i][j] = 0.f;
  for (int kk = 0; kk < 64; ++kk) {
    float4 a = *(const float4*)&sA[kk][ty * 4];
    float4 bq = *(const float4*)&sB[kk][tx * 4];
    float aa[4] = {a.x, a.y, a.z, a.w}, bb[4] = {bq.x, bq.y, bq.z, bq.w};
#pragma unroll
    for (int i = 0; i < 4; ++i)
#pragma unroll
      for (int j = 0; j < 4; ++j) acc[i][j] += aa[i] * bb[j];
  }
  int c0 = ct * 64 + tx * 4;
#pragma unroll
  for (int i = 0; i < 4; ++i) {
    size_t row = (size_t)row0 + ty * 4 + i;
    float4 o;
    if (c0 < 128) {
      o.x = acc[i][0]; o.y = acc[i][1]; o.z = acc[i][2]; o.w = acc[i][3];
      *(float4*)(T3 + row * 128 + c0) = o;
    } else {
      o.x = silu_(acc[i][0]); o.y = silu_(acc[i][1]); o.z = silu_(acc[i][2]); o.w = silu_(acc[i][3]);
      *(float4*)(T4 + row * 128 + (c0 - 128)) = o;
    }
  }
}

// ---------------- K3: depthwise conv 3x3 + SiLU -> U0, U1, and Ysum = sumDs*u ----------------
__global__ __launch_bounds__(256) void k3_conv2(
    const float* __restrict__ T3, const void* cw, const void* cb, const void* Ds,
    const int* __restrict__ flag,
    float* __restrict__ U0, float* __restrict__ U1, float* __restrict__ Ysum)
{
  bool isb = (*flag != 0);
  int e = blockIdx.x >> 6, h = blockIdx.x & 63, dc = blockIdx.y;
  int t = threadIdx.x;
  __shared__ float sI[3][66][65];  // [row][1+w][d]
  for (int idx = t; idx < 3 * 2 * 64; idx += 256) {
    int r = idx / 128, rem = idx % 128, side = rem >> 6, d = rem & 63;
    sI[r][side * 65][d] = 0.f;
  }
  for (int idx = t; idx < 3 * 64 * 64; idx += 256) {
    int r = idx >> 12, rem = idx & 4095, w = rem >> 6, d = rem & 63;
    int hh = h + r - 1;
    float v = 0.f;
    if (hh >= 0 && hh < 64) v = T3[((size_t)e * 4096 + hh * 64 + w) * 128 + dc * 64 + d];
    sI[r][1 + w][d] = v;
  }
  __syncthreads();
  int d = t & 63, wq = t >> 6;
  int c2 = dc * 64 + d;
  float wt[9];
#pragma unroll
  for (int m = 0; m < 9; ++m) wt[m] = LD(cw, c2 * 9 + m, isb);
  float bias = LD(cb, c2, isb);
  float sd = LD(Ds, c2, isb) + LD(Ds, 128 + c2, isb) + LD(Ds, 256 + c2, isb) + LD(Ds, 384 + c2, isb);
  size_t eb = (size_t)e * 4096;
#pragma unroll
  for (int i = 0; i < 16; ++i) {
    int w = wq * 16 + i;
    float s = bias;
#pragma unroll
    for (int kh = 0; kh < 3; ++kh)
#pragma unroll
      for (int kw = 0; kw < 3; ++kw)
        s += wt[kh * 3 + kw] * sI[kh][w + kw][d];
    s = silu_(s);
    U0[(eb + h * 64 + w) * 128 + c2] = s;
    U1[(eb + w * 64 + h) * 128 + c2] = s;
    Ysum[(eb + h * 64 + w) * 128 + c2] = sd * s;
  }
}

// ---------------- K5: x_dbl einsum -> dts4 [l][4], Bb2/Cb2 [l][n] (scan order) ----------------
__global__ __launch_bounds__(256) void k5_xdbl(
    const float* __restrict__ U0, const float* __restrict__ U1,
    const void* xpw, const int* __restrict__ flag,
    float* __restrict__ dts4, float* __restrict__ Bb2, float* __restrict__ Cb2)
{
  bool isb = (*flag != 0);
  int lt = blockIdx.x;   // 64 tiles of 64 along L
  int ek = blockIdx.y;   // e*4+k
  int e = ek >> 2, k = ek & 3;
  int ls0 = lt * 64;
  int t = threadIdx.x;
  __shared__ float sU[64][132];   // [l][d]
  __shared__ float sW[36][132];   // [c][d]
  for (int idx = t; idx < 36 * 128; idx += 256) {
    int c = idx >> 7, d = idx & 127;
    sW[c][d] = LD(xpw, ((size_t)k * 36 + c) * 128 + d, isb);
  }
  const float* usrc = (k & 1) ? U1 : U0;
  bool rev = (k >= 2);
  for (int idx = t; idx < 2048; idx += 256) {
    int l = idx >> 5, d4 = (idx & 31) * 4;
    int row = rev ? (4095 - ls0 - l) : (ls0 + l);
    float4 v = *(const float4*)(usrc + ((size_t)e * 4096 + row) * 128 + d4);
    *(float4*)&sU[l][d4] = v;
  }
  __syncthreads();
  int l = t & 63, cg = t >> 6;
  float acc[9];
#pragma unroll
  for (int j = 0; j < 9; ++j) acc[j] = 0.f;
  for (int dd = 0; dd < 32; ++dd) {
    float4 u4 = *(const float4*)&sU[l][dd * 4];
    float ua[4] = {u4.x, u4.y, u4.z, u4.w};
#pragma unroll
    for (int j = 0; j < 9; ++j) {
      float4 w4 = *(const float4*)&sW[cg * 9 + j][dd * 4];
      acc[j] += ua[0] * w4.x + ua[1] * w4.y + ua[2] * w4.z + ua[3] * w4.w;
    }
  }
  size_t row = (size_t)ek * 4096 + ls0 + l;
  if (cg == 0) {
    float4 o; o.x = acc[0]; o.y = acc[1]; o.z = acc[2]; o.w = acc[3];
    *(float4*)(dts4 + row * 4) = o;
#pragma unroll
    for (int j = 4; j < 9; ++j) Bb2[row * 16 + (j - 4)] = acc[j];
  } else {
#pragma unroll
    for (int j = 0; j < 9; ++j) {
      int c = cg * 9 + j;
      if (c < 20) Bb2[row * 16 + (c - 4)] = acc[j];
      else Cb2[row * 16 + (c - 20)] = acc[j];
    }
  }
}

// ---------------- K6a: chunk-local scan, delta fused -> Hs ----------------
template<int NSTEPS>
__global__ __launch_bounds__(128) void k6a_chunk(
    const float* __restrict__ U0, const float* __restrict__ U1,
    const float* __restrict__ dts4, const float* __restrict__ Bb2,
    const void* alog, const void* dtw, const void* dtb, const int* __restrict__ flag,
    float* __restrict__ Hs)
{
  bool isb = (*flag != 0);
  int chunk = blockIdx.x, ek = blockIdx.y;
  int e = ek >> 2, k = ek & 3;
  int d = threadIdx.x;
  int ls0 = chunk * NSTEPS;
  float a2[16];
#pragma unroll
  for (int n = 0; n < 16; ++n)
    a2[n] = -__expf(LD(alog, ((size_t)k * 128 + d) * 16 + n, isb)) * 1.44269504f;
  float w0 = LD(dtw, ((size_t)k * 128 + d) * 4 + 0, isb);
  float w1 = LD(dtw, ((size_t)k * 128 + d) * 4 + 1, isb);
  float w2 = LD(dtw, ((size_t)k * 128 + d) * 4 + 2, isb);
  float w3 = LD(dtw, ((size_t)k * 128 + d) * 4 + 3, isb);
  float bd = LD(dtb, k * 128 + d, isb);
  float h[16];
#pragma unroll
  for (int n = 0; n < 16; ++n) h[n] = 0.f;
  float sdelta = 0.f;
  const float* usrc = (k & 1) ? U1 : U0;
  const bool rev = (k >= 2);
  const float* ubase = usrc + (size_t)e * 4096 * 128 + d;
  const float4* sbase = (const float4*)(dts4 + ((size_t)ek * 4096 + ls0) * 4);
  const float4* bbase = (const float4*)(Bb2 + ((size_t)ek * 4096 + ls0) * 16);
#pragma unroll 2
  for (int t = 0; t < NSTEPS; ++t) {
    float4 s4 = sbase[t];
    float xv = bd + w0 * s4.x + w1 * s4.y + w2 * s4.z + w3 * s4.w;
    float dlt = softplus_(xv);
    int urow = rev ? (4095 - ls0 - t) : (ls0 + t);
    float uu = ubase[(size_t)urow * 128];
    float du = dlt * uu;
    float4 b0 = bbase[t * 4 + 0], b1 = bbase[t * 4 + 1], b2 = bbase[t * 4 + 2], b3 = bbase[t * 4 + 3];
    float bb[16] = {b0.x,b0.y,b0.z,b0.w, b1.x,b1.y,b1.z,b1.w,
                    b2.x,b2.y,b2.z,b2.w, b3.x,b3.y,b3.z,b3.w};
    sdelta += dlt;
#pragma unroll
    for (int n = 0; n < 16; ++n) {
      float dA = EXP2R(dlt * a2[n]);
      h[n] = fmaf(dA, h[n], du * bb[n]);
    }
  }
  float2* hp = (float2*)Hs + ((size_t)chunk * 65536 + ek * 2048 + d * 16);
#pragma unroll
  for (int n = 0; n < 16; ++n) {
    float2 o; o.x = h[n]; o.y = EXP2R(a2[n] * sdelta);  // telescoped prod(dA)
    hp[n] = o;
  }
}

// ---------------- K6b: carry scan over chunk summaries; carry written IN-PLACE into Hs.x ----------------
__global__ __launch_bounds__(256) void k6b_carry(
    float* __restrict__ Hs, int nchunks)
{
  int idx = blockIdx.x * 256 + threadIdx.x;   // 65536 rows
  float2* hs = (float2*)Hs;
  float carry = 0.f;
  for (int c = 0; c < nchunks; ++c) {
    float2 v = hs[(size_t)c * 65536 + idx];
    Hs[((size_t)c * 65536 + idx) * 2] = carry;   // overwrite .x with incoming state
    carry = v.x + v.y * carry;
  }
}

// ---------------- K6c: seeded chunk scan, delta fused; y atomically merged into Ysum ----------------
template<int NSTEPS>
__global__ __launch_bounds__(128) void k6c_apply(
    const float* __restrict__ U0, const float* __restrict__ U1,
    float* __restrict__ Ysum, const float* __restrict__ dts4,
    const float* __restrict__ Bb2, const float* __restrict__ Cb2,
    const void* alog, const void* dtw, const void* dtb,
    const float* __restrict__ Hs, const int* __restrict__ flag)
{
  bool isb = (*flag != 0);
  int chunk = blockIdx.x, ek = blockIdx.y;
  int e = ek >> 2, k = ek & 3;
  int d = threadIdx.x;
  int ls0 = chunk * NSTEPS;
  float a2[16];
#pragma unroll
  for (int n = 0; n < 16; ++n)
    a2[n] = -__expf(LD(alog, ((size_t)k * 128 + d) * 16 + n, isb)) * 1.44269504f;
  float w0 = LD(dtw, ((size_t)k * 128 + d) * 4 + 0, isb);
  float w1 = LD(dtw, ((size_t)k * 128 + d) * 4 + 1, isb);
  float w2 = LD(dtw, ((size_t)k * 128 + d) * 4 + 2, isb);
  float w3 = LD(dtw, ((size_t)k * 128 + d) * 4 + 3, isb);
  float bd = LD(dtb, k * 128 + d, isb);
  float h[16];
  const float* hp = Hs + ((size_t)chunk * 65536 + ek * 2048 + d * 16) * 2;
#pragma unroll
  for (int n = 0; n < 16; ++n) h[n] = hp[2 * n];
  const float* usrc = (k & 1) ? U1 : U0;
  const bool rev = (k >= 2);
  float* ybase = Ysum + (size_t)e * 4096 * 128 + d;
  const float* ubase = usrc + (size_t)e * 4096 * 128 + d;
  const float4* sbase = (const float4*)(dts4 + ((size_t)ek * 4096 + ls0) * 4);
  const float4* bbase = (const float4*)(Bb2 + ((size_t)ek * 4096 + ls0) * 16);
  const float4* cbase = (const float4*)(Cb2 + ((size_t)ek * 4096 + ls0) * 16);
#pragma unroll 2
  for (int t = 0; t < NSTEPS; ++t) {
    float4 s4 = sbase[t];
    float xv = bd + w0 * s4.x + w1 * s4.y + w2 * s4.z + w3 * s4.w;
    float dlt = softplus_(xv);
    int urow = rev ? (4095 - ls0 - t) : (ls0 + t);
    float uu = ubase[(size_t)urow * 128];
    float du = dlt * uu;
    float4 b0 = bbase[t * 4 + 0], b1 = bbase[t * 4 + 1], b2 = bbase[t * 4 + 2], b3 = bbase[t * 4 + 3];
    float4 c0 = cbase[t * 4 + 0], c1 = cbase[t * 4 + 1], c2 = cbase[t * 4 + 2], c3 = cbase[t * 4 + 3];
    float bb[16] = {b0.x,b0.y,b0.z,b0.w, b1.x,b1.y,b1.z,b1.w,
                    b2.x,b2.y,b2.z,b2.w, b3.x,b3.y,b3.z,b3.w};
    float cc[16] = {c0.x,c0.y,c0.z,c0.w, c1.x,c1.y,c1.z,c1.w,
                    c2.x,c2.y,c2.z,c2.w, c3.x,c3.y,c3.z,c3.w};
    float ya = 0.f, yb = 0.f, yc = 0.f, yd = 0.f;
#pragma unroll
    for (int n = 0; n < 16; n += 4) {
      float dA0 = EXP2R(dlt * a2[n]);
      float dA1 = EXP2R(dlt * a2[n+1]);
      float dA2 = EXP2R(dlt * a2[n+2]);
      float dA3 = EXP2R(dlt * a2[n+3]);
      h[n]   = fmaf(dA0, h[n],   du * bb[n]);
      h[n+1] = fmaf(dA1, h[n+1], du * bb[n+1]);
      h[n+2] = fmaf(dA2, h[n+2], du * bb[n+2]);
      h[n+3] = fmaf(dA3, h[n+3], du * bb[n+3]);
      ya = fmaf(h[n],   cc[n],   ya);
      yb = fmaf(h[n+1], cc[n+1], yb);
      yc = fmaf(h[n+2], cc[n+2], yc);
      yd = fmaf(h[n+3], cc[n+3], yd);
    }
    // map scan position -> output spatial row, then atomic merge
    int p = ls0 + t;
    int orow;
    if (k == 0)      orow = p;
    else if (k == 1) orow = ((p & 63) << 6) | (p >> 6);
    else if (k == 2) orow = 4095 - p;
    else { int q = 4095 - p; orow = ((q & 63) << 6) | (q >> 6); }
    atomicAdd(ybase + (size_t)orow * 128, (ya + yb) + (yc + yd));
  }
}

// ---------------- K7b: out_norm LN * silu(z) -> out_proj -> +residual -> P (E,64,L) ----------------
__global__ __launch_bounds__(256) void k7b_out(
    const float* __restrict__ Ysum, const float* __restrict__ T4,
    const float* __restrict__ T1,
    const void* ong, const void* onb, const void* opw, const void* scale_p,
    const int* __restrict__ flag,
    float* __restrict__ P)
{
  bool isb = (*flag != 0);
  int bid = blockIdx.x; int e = bid >> 7, lt = bid & 127;
  int l0 = lt * 32;
  int t = threadIdx.x;
  __shared__ float sY[32][132];
  __shared__ float sWo[64][132];
  __shared__ float sMu[32], sRs[32];
  __shared__ float sPs[32][8], sPq[32][8];
  __shared__ float sP[64][33];
  for (int idx = t; idx < 8192; idx += 256) sWo[idx >> 7][idx & 127] = LD(opw, idx, isb);
  for (int q = t; q < 1024; q += 256) {
    int l = q >> 5, d4 = (q & 31) * 4;
    float4 v = *(const float4*)(Ysum + ((size_t)e * 4096 + l0 + l) * 128 + d4);
    *(float4*)&sY[l][d4] = v;
  }
  __syncthreads();
  {
    int l = t & 31, g = t >> 5;
    float s = 0.f, q2 = 0.f;
#pragma unroll
    for (int j = 0; j < 16; ++j) { float v = sY[l][g * 16 + j]; s += v; q2 += v * v; }
    sPs[l][g] = s; sPq[l][g] = q2;
  }
  __syncthreads();
  if (t < 32) {
    float s = 0.f, q2 = 0.f;
#pragma unroll
    for (int g = 0; g < 8; ++g) { s += sPs[t][g]; q2 += sPq[t][g]; }
    float mu = s * (1.f / 128.f);
    float var = q2 * (1.f / 128.f) - mu * mu;
    sMu[t] = mu; sRs[t] = rsqrtf(var + 1e-5f);
  }
  __syncthreads();
  for (int idx = t; idx < 4096; idx += 256) {
    int l = idx >> 7, dd2 = idx & 127;
    float v = (sY[l][dd2] - sMu[l]) * sRs[l] * LD(ong, dd2, isb) + LD(onb, dd2, isb);
    v *= T4[((size_t)e * 4096 + l0 + l) * 128 + dd2];
    sY[l][dd2] = v;
  }
  __syncthreads();
  float ops = 1.f + LD(scale_p, 0, isb);
  {
    int l = t & 31, cg = t >> 5;
    float acc[8];
#pragma unroll
    for (int j = 0; j < 8; ++j) acc[j] = 0.f;
    for (int dd = 0; dd < 32; ++dd) {
      float4 v4 = *(const float4*)&sY[l][dd * 4];
      float va[4] = {v4.x, v4.y, v4.z, v4.w};
#pragma unroll
      for (int j = 0; j < 8; ++j) {
        float4 w4 = *(const float4*)&sWo[cg * 8 + j][dd * 4];
        acc[j] += va[0] * w4.x + va[1] * w4.y + va[2] * w4.z + va[3] * w4.w;
      }
    }
#pragma unroll
    for (int j = 0; j < 8; ++j) {
      int c = cg * 8 + j;
      sP[c][l] = acc[j] + ops * T1[((size_t)e * 4096 + l0 + l) * 64 + c];
    }
  }
  __syncthreads();
  for (int q = t; q < 512; q += 256) {
    int c = q >> 3, lq = (q & 7) * 4;
    float4 o; o.x = sP[c][lq]; o.y = sP[c][lq+1]; o.z = sP[c][lq+2]; o.w = sP[c][lq+3];
    *(float4*)(P + ((size_t)e * 64 + c) * 4096 + l0 + lq) = o;
  }
}

// ---------------- K7c: instance-norm over L per (e,c) + leaky relu + out ----------------
__global__ __launch_bounds__(256) void k7c_final(
    const float* __restrict__ P, const void* gamma, const void* beta,
    const int* __restrict__ flag, void* __restrict__ out)
{
  bool isb = (*flag != 0);
  int bid = blockIdx.x; int e = bid >> 6, c = bid & 63;
  int b = e & 3, br = e >> 2;
  int cg = br * 64 + c;
  int t = threadIdx.x;
  const float* p = P + ((size_t)e * 64 + c) * 4096;
  float s = 0.f, q2 = 0.f;
  for (int q = t; q < 1024; q += 256) {
    float4 v = *(const float4*)(p + q * 4);
    s += v.x + v.y + v.z + v.w;
    q2 += v.x * v.x + v.y * v.y + v.z * v.z + v.w * v.w;
  }
#pragma unroll
  for (int off = 1; off < 64; off <<= 1) { s += __shfl_xor(s, off); q2 += __shfl_xor(q2, off); }
  __shared__ float rS[4], rQ[4];
  if ((t & 63) == 0) { rS[t >> 6] = s; rQ[t >> 6] = q2; }
  __syncthreads();
  float ts = rS[0] + rS[1] + rS[2] + rS[3];
  float tq = rQ[0] + rQ[1] + rQ[2] + rQ[3];
  float mu = ts * (1.f / 4096.f);
  float var = tq * (1.f / 4096.f) - mu * mu;
  float rsg = rsqrtf(var + 1e-5f);
  float gm = LD(gamma, cg, isb), bt = LD(beta, cg, isb);
  size_t obase = ((size_t)(b * 128 + cg)) * 4096;
  for (int q = t; q < 1024; q += 256) {
    float4 v = *(const float4*)(p + q * 4);
    float o0 = (v.x - mu) * rsg * gm + bt; o0 = o0 > 0.f ? o0 : 0.01f * o0;
    float o1 = (v.y - mu) * rsg * gm + bt; o1 = o1 > 0.f ? o1 : 0.01f * o1;
    float o2 = (v.z - mu) * rsg * gm + bt; o2 = o2 > 0.f ? o2 : 0.01f * o2;
    float o3 = (v.w - mu) * rsg * gm + bt; o3 = o3 > 0.f ? o3 : 0.01f * o3;
    if (isb) {
      unsigned short* op = (unsigned short*)out + obase;
      unsigned lo = (unsigned)f2bf(o0) | ((unsigned)f2bf(o1) << 16);
      unsigned hi = (unsigned)f2bf(o2) | ((unsigned)f2bf(o3) << 16);
      uint2 u; u.x = lo; u.y = hi;
      *(uint2*)(op + q * 4) = u;
    } else {
      float* op = (float*)out + obase;
      float4 o; o.x = o0; o.y = o1; o.z = o2; o.w = o3;
      *(float4*)(op + q * 4) = o;
    }
  }
}

extern "C" void kernel_launch(void* const* d_in, const int* in_sizes, int n_in,
                              void* d_out, int out_size, void* d_ws, size_t ws_size,
                              hipStream_t stream) {
  (void)in_sizes; (void)n_in; (void)out_size;
  const void* x      = d_in[0];
  const void* dw_w   = d_in[1];
  const void* dw_b   = d_in[2];
  const void* scale  = d_in[3];
  const void* ln1_g  = d_in[4];
  const void* ln1_b  = d_in[5];
  const void* ipw    = d_in[6];
  const void* conv_w = d_in[7];
  const void* conv_b = d_in[8];
  const void* xpw    = d_in[9];
  const void* dtw    = d_in[10];
  const void* dtb    = d_in[11];
  const void* alog   = d_in[12];
  const void* Ds     = d_in[13];
  const void* ong    = d_in[14];
  const void* onb    = d_in[15];
  const void* opw    = d_in[16];
  const void* ing    = d_in[17];
  const void* inb    = d_in[18];

  float* ws = (float*)d_ws;
  float* T1  = ws;                   // (E,L,64)  xd rows                 8.4MB
  float* T2  = ws + 2097152;         // (E,L,64)  xln -> dts4 -> P        8.4MB
  float* T3  = ws + 4194304;         // (E,L,128) conv-in -> Bb2+Cb2      16.8MB
  float* T4  = ws + 8388608;         // (E,L,128) silu(z)                 16.8MB
  float* U0  = ws + 12582912;        // (E,L,128) xc rows [h*64+w][d]     16.8MB
  float* U1  = ws + 16777216;        // (E,L,128) xc rows [w*64+h][d]     16.8MB
  float* Ysum = ws + 20971520;       // (E,L,128) direction-merged y      16.8MB
  float* Bb2 = T3;                   // (EK,L,16)
  float* Cb2 = T3 + 2097152;         // (EK,L,16)
  float* Hs  = ws + 37748736;        // nch x 65536 float2 (carry in-place)
  float* dts4 = T2;                  // (EK,L,4) — overlays dead xln

  size_t base_f = 37748736;
  size_t need64 = (base_f + (size_t)64 * 65536 * 2 + 16) * 4;
  int nch = (ws_size >= need64) ? 64 : 32;
  int* flag = (int*)(ws + base_f + (size_t)nch * 65536 * 2);

  hipLaunchKernelGGL(kdet, dim3(1), dim3(64), 0, stream, x, flag);
  hipLaunchKernelGGL(k0_conv_ln, dim3(512), dim3(256), 0, stream, x, dw_w, dw_b, ln1_g, ln1_b, flag, T1, T2);
  hipLaunchKernelGGL(k2_inproj, dim3(512, 4), dim3(256), 0, stream, T2, ipw, flag, T3, T4);
  hipLaunchKernelGGL(k3_conv2, dim3(512, 2), dim3(256), 0, stream, T3, conv_w, conv_b, Ds, flag, U0, U1, Ysum);
  hipLaunchKernelGGL(k5_xdbl, dim3(64, 32), dim3(256), 0, stream, U0, U1, xpw, flag, dts4, Bb2, Cb2);
  if (nch == 64) {
    hipLaunchKernelGGL(k6a_chunk<64>, dim3(64, 32), dim3(128), 0, stream, U0, U1, dts4, Bb2, alog, dtw, dtb, flag, Hs);
    hipLaunchKernelGGL(k6b_carry, dim3(256), dim3(256), 0, stream, Hs, 64);
    hipLaunchKernelGGL(k6c_apply<64>, dim3(64, 32), dim3(128), 0, stream, U0, U1, Ysum, dts4, Bb2, Cb2, alog, dtw, dtb, Hs, flag);
  } else {
    hipLaunchKernelGGL(k6a_chunk<128>, dim3(32, 32), dim3(128), 0, stream, U0, U1, dts4, Bb2, alog, dtw, dtb, flag, Hs);
    hipLaunchKernelGGL(k6b_carry, dim3(256), dim3(256), 0, stream, Hs, 32);
    hipLaunchKernelGGL(k6c_apply<128>, dim3(32, 32), dim3(128), 0, stream, U0, U1, Ysum, dts4, Bb2, Cb2, alog, dtw, dtb, Hs, flag);
  }
  hipLaunchKernelGGL(k7b_out, dim3(1024), dim3(256), 0, stream, Ysum, T4, T1, ong, onb, opw, scale, flag, T2);
  hipLaunchKernelGGL(k7c_final, dim3(512), dim3(256), 0, stream, T2, ing, inb, flag, d_out);
}